// Round 7
// baseline (429.183 us; speedup 1.0000x reference)
//
#include <hip/hip_runtime.h>
#include <stdint.h>

#define NN 50000
#define NE 800000
#define DIM 256

// hist privatization params
#define HB 128      // hist blocks
#define HT 512      // hist threads/block
#define HALF 25000  // nodes per range (2 ranges cover NN); also words-per-block stride
#define HWORDS 12500 // packed words per range (2 nodes/word)

typedef __bf16 bf16x8 __attribute__((ext_vector_type(8)));
typedef float f32x4 __attribute__((ext_vector_type(4)));

__device__ __forceinline__ unsigned short f2bf(float f) {
  union { float f; unsigned u; } v; v.f = f;
  unsigned r = v.u + 0x7fffu + ((v.u >> 16) & 1u);
  return (unsigned short)(r >> 16);
}

// ---------------- LDS-privatized degree histograms (no global atomics) ----------------
__global__ __launch_bounds__(HT) void hist_kernel(const int* __restrict__ src,
                                                  const int* __restrict__ dst,
                                                  unsigned* __restrict__ Hs,
                                                  unsigned* __restrict__ Hd) {
  __shared__ unsigned lds[HWORDS];  // 50 KB
  const int tid = threadIdx.x;
  const int b = blockIdx.x;
#pragma unroll
  for (int phase = 0; phase < 4; ++phase) {
    const int* arr = (phase < 2) ? src : dst;
    unsigned* H = (phase < 2) ? Hs : Hd;
    const int r = phase & 1;
    const int lo = r * HALF;
    for (int w = tid; w < HWORDS; w += HT) lds[w] = 0u;
    __syncthreads();
    for (int e = b * HT + tid; e < NE; e += HB * HT) {
      unsigned local = (unsigned)(arr[e] - lo);
      if (local < (unsigned)HALF)
        atomicAdd(&lds[local >> 1], 1u << ((local & 1) * 16));
    }
    __syncthreads();
    for (int w = tid; w < HWORDS; w += HT)
      H[(size_t)b * HALF + r * HWORDS + w] = lds[w];
    __syncthreads();
  }
}

// ---------------- reduce hists -> degrees + norms + per-block dst prefixes + hg zero ----------------
__global__ void reduce_norm_kernel(const unsigned* __restrict__ Hs,
                                   const unsigned* __restrict__ Hd,
                                   unsigned* __restrict__ Pd,
                                   int* __restrict__ in_cnt,
                                   float* __restrict__ norm_s,
                                   float* __restrict__ norm_d,
                                   float* __restrict__ hg) {
  int w = blockIdx.x * blockDim.x + threadIdx.x;
  if (blockIdx.x == 0) {  // zero pooled output (512 floats)
    hg[threadIdx.x] = 0.f;
    hg[256 + threadIdx.x] = 0.f;
  }
  if (w >= 2 * HWORDS) return;
  unsigned ss = 0, dd = 0;
  for (int b = 0; b < HB; ++b) {
    Pd[(size_t)b * HALF + w] = dd;
    ss += Hs[(size_t)b * HALF + w];
    dd += Hd[(size_t)b * HALF + w];
  }
  int r = (w >= HWORDS) ? 1 : 0;
  int lw = w - r * HWORDS;
  int n0 = r * HALF + lw * 2;
  unsigned s0 = ss & 0xffffu, s1 = ss >> 16;
  unsigned d0 = dd & 0xffffu, d1 = dd >> 16;
  in_cnt[n0] = (int)d0;
  in_cnt[n0 + 1] = (int)d1;
  norm_s[n0] = rsqrtf(fmaxf((float)s0, 1.0f));
  norm_s[n0 + 1] = rsqrtf(fmaxf((float)s1, 1.0f));
  norm_d[n0] = rsqrtf(fmaxf((float)d0, 1.0f));
  norm_d[n0 + 1] = rsqrtf(fmaxf((float)d1, 1.0f));
}

// ---------------- exclusive scan, single pass (49 nodes/thread, 1 barrier) ----------------
#define SCAN_P 49  // 1024*49 = 50176 >= NN+1
__global__ __launch_bounds__(1024) void scan_kernel(const int* __restrict__ in_cnt,
                                                    int* __restrict__ row_ptr) {
  __shared__ int wsum[16];
  int tid = threadIdx.x;
  int lane = tid & 63, wave = tid >> 6;
  int base = tid * SCAN_P;
  int v[SCAN_P];
  int tsum = 0;
#pragma unroll
  for (int j = 0; j < SCAN_P; ++j) {
    int i = base + j;
    int x = (i < NN) ? in_cnt[i] : 0;
    v[j] = tsum;
    tsum += x;
  }
  int incl = tsum;
#pragma unroll
  for (int off = 1; off < 64; off <<= 1) {
    int t = __shfl_up(incl, off, 64);
    if (lane >= off) incl += t;
  }
  if (lane == 63) wsum[wave] = incl;
  __syncthreads();
  int waveoff = 0;
  for (int w = 0; w < wave; ++w) waveoff += wsum[w];
  int texcl = waveoff + (incl - tsum);
#pragma unroll
  for (int j = 0; j < SCAN_P; ++j) {
    int i = base + j;
    if (i < NN) row_ptr[i] = texcl + v[j];
  }
  if (tid == 1023) row_ptr[NN] = texcl + tsum;  // base > NN here, so texcl+tsum == grand total
}

// ---------------- CSR fill, atomic-free (rank via LDS, base via Pd prefix) ----------------
__global__ __launch_bounds__(HT) void fill_kernel(const int* __restrict__ src,
                                                  const int* __restrict__ dst,
                                                  const int* __restrict__ row_ptr,
                                                  const unsigned* __restrict__ Pd,
                                                  int* __restrict__ colx) {
  __shared__ unsigned lds[HWORDS];
  const int tid = threadIdx.x;
  const int b = blockIdx.x;
#pragma unroll
  for (int r = 0; r < 2; ++r) {
    const int lo = r * HALF;
    for (int w = tid; w < HWORDS; w += HT) lds[w] = 0u;
    __syncthreads();
    for (int e = b * HT + tid; e < NE; e += HB * HT) {
      int n = dst[e];
      unsigned local = (unsigned)(n - lo);
      if (local < (unsigned)HALF) {
        int sh = (local & 1) * 16;
        unsigned old = atomicAdd(&lds[local >> 1], 1u << sh);
        unsigned rank = (old >> sh) & 0xffffu;
        unsigned pref = (Pd[(size_t)b * HALF + r * HWORDS + (local >> 1)] >> sh) & 0xffffu;
        colx[row_ptr[n] + (int)pref + (int)rank] = src[e];
      }
    }
    __syncthreads();
  }
}

// ---------------- fused prep: cast feat (scaled by norm_s) + swizzle W0/W1 ----------------
__device__ __forceinline__ void swizzleW_body(const float* __restrict__ W,
                                              unsigned short* __restrict__ Wb, int idx) {
  int lane = idx & 63;
  int blk = idx >> 6;
  int kc = blk & 7, nt = blk >> 3;
  int kbase = kc * 32 + (lane >> 4) * 8;
  int col = nt * 16 + (lane & 15);
  ushort4 o0, o1;
  o0.x = f2bf(W[(size_t)(kbase + 0) * DIM + col]);
  o0.y = f2bf(W[(size_t)(kbase + 1) * DIM + col]);
  o0.z = f2bf(W[(size_t)(kbase + 2) * DIM + col]);
  o0.w = f2bf(W[(size_t)(kbase + 3) * DIM + col]);
  o1.x = f2bf(W[(size_t)(kbase + 4) * DIM + col]);
  o1.y = f2bf(W[(size_t)(kbase + 5) * DIM + col]);
  o1.z = f2bf(W[(size_t)(kbase + 6) * DIM + col]);
  o1.w = f2bf(W[(size_t)(kbase + 7) * DIM + col]);
  ((ushort4*)Wb)[idx * 2 + 0] = o0;
  ((ushort4*)Wb)[idx * 2 + 1] = o1;
}

__global__ void prep_kernel(const float* __restrict__ feat, const float* __restrict__ norm_s,
                            unsigned short* __restrict__ featb,
                            const float* __restrict__ W0, unsigned short* __restrict__ Wb0,
                            const float* __restrict__ W1, unsigned short* __restrict__ Wb1) {
  int blk = blockIdx.x;
  if (blk < 12500) {
    int i = blk * 256 + threadIdx.x;
    float s = norm_s[i >> 6];
    float4 v = ((const float4*)feat)[i];
    ushort4 o;
    o.x = f2bf(v.x * s); o.y = f2bf(v.y * s); o.z = f2bf(v.z * s); o.w = f2bf(v.w * s);
    ((ushort4*)featb)[i] = o;
  } else if (blk < 12532) {
    swizzleW_body(W0, Wb0, (blk - 12500) * 256 + threadIdx.x);
  } else {
    swizzleW_body(W1, Wb1, (blk - 12532) * 256 + threadIdx.x);
  }
}

// ---------------- gather-aggregate (X pre-scaled by norm_s): agg[n] = nd[n]*sum X[c] ----------------
__device__ __forceinline__ void acc_row(float* a, uint4 p) {
  a[0] += __uint_as_float(p.x << 16);
  a[1] += __uint_as_float(p.x & 0xffff0000u);
  a[2] += __uint_as_float(p.y << 16);
  a[3] += __uint_as_float(p.y & 0xffff0000u);
  a[4] += __uint_as_float(p.z << 16);
  a[5] += __uint_as_float(p.z & 0xffff0000u);
  a[6] += __uint_as_float(p.w << 16);
  a[7] += __uint_as_float(p.w & 0xffff0000u);
}

// wave per node; half-wave covers the 512B row (16B/lane); 4 rows in flight per half-wave
__global__ __launch_bounds__(256) void agg_kernel(const unsigned short* __restrict__ X,
                                                  unsigned short* __restrict__ agg,
                                                  const int* __restrict__ row_ptr,
                                                  const int* __restrict__ colx,
                                                  const float* __restrict__ norm_d) {
  int wave = threadIdx.x >> 6;
  int lane = threadIdx.x & 63;
  int half = lane >> 5;
  int sl = lane & 31;
  int node = blockIdx.x * 4 + wave;
  if (node >= NN) return;
  int beg = row_ptr[node];
  int end = row_ptr[node + 1];

  float a[8];
#pragma unroll
  for (int j = 0; j < 8; ++j) a[j] = 0.f;

  int i = beg;
  // main: 8 edges/iter; half-wave h takes edges [i+4h, i+4h+4) -> 4 rows in flight/lane
  for (; i + 8 <= end; i += 8) {
    int e0 = i + half * 4;
    int c0 = colx[e0 + 0];
    int c1 = colx[e0 + 1];
    int c2 = colx[e0 + 2];
    int c3 = colx[e0 + 3];
    uint4 r0 = *(const uint4*)(X + (size_t)c0 * DIM + sl * 8);
    uint4 r1 = *(const uint4*)(X + (size_t)c1 * DIM + sl * 8);
    uint4 r2 = *(const uint4*)(X + (size_t)c2 * DIM + sl * 8);
    uint4 r3 = *(const uint4*)(X + (size_t)c3 * DIM + sl * 8);
    acc_row(a, r0);
    acc_row(a, r1);
    acc_row(a, r2);
    acc_row(a, r3);
  }
  // remainder: 4, 2, 1
  if (i + 4 <= end) {
    int c0 = colx[i + half];
    int c1 = colx[i + 2 + half];
    uint4 r0 = *(const uint4*)(X + (size_t)c0 * DIM + sl * 8);
    uint4 r1 = *(const uint4*)(X + (size_t)c1 * DIM + sl * 8);
    acc_row(a, r0);
    acc_row(a, r1);
    i += 4;
  }
  if (i + 2 <= end) {
    int c = colx[i + half];
    uint4 r = *(const uint4*)(X + (size_t)c * DIM + sl * 8);
    acc_row(a, r);
    i += 2;
  }
  if (i < end && half == 0) {
    int c = colx[i];
    uint4 r = *(const uint4*)(X + (size_t)c * DIM + sl * 8);
    acc_row(a, r);
  }
#pragma unroll
  for (int j = 0; j < 8; ++j) a[j] += __shfl_xor(a[j], 32, 64);

  if (half == 0) {
    float nd = norm_d[node];
    uint4 o;
    o.x = (unsigned)f2bf(a[0] * nd) | ((unsigned)f2bf(a[1] * nd) << 16);
    o.y = (unsigned)f2bf(a[2] * nd) | ((unsigned)f2bf(a[3] * nd) << 16);
    o.z = (unsigned)f2bf(a[4] * nd) | ((unsigned)f2bf(a[5] * nd) << 16);
    o.w = (unsigned)f2bf(a[6] * nd) | ((unsigned)f2bf(a[7] * nd) << 16);
    *(uint4*)(agg + (size_t)node * DIM + sl * 8) = o;
  }
}

// ---------------- MFMA GEMM (32-row tile) + bias + PReLU + coalesced epilogue + pooling ----------------
#define LDSROW 264   // bf16 row stride for A tile
#define FROW 260     // f32 row stride for epilogue staging
__global__ __launch_bounds__(256) void gemm_mfma_kernel(const unsigned short* __restrict__ A,
                                                        const unsigned short* __restrict__ Wb,
                                                        const float* __restrict__ bias,
                                                        const float* __restrict__ prelu_a_ptr,
                                                        const float* __restrict__ norm_s,
                                                        float* __restrict__ C,
                                                        unsigned short* __restrict__ Cb,
                                                        float* __restrict__ hg) {
  __shared__ unsigned short As[32 * LDSROW];
  int tid = threadIdx.x;
  int r0 = blockIdx.x * 32;
#pragma unroll
  for (int p = 0; p < 4; ++p) {
    int idx = p * 256 + tid;
    int row = idx >> 5;
    int seg = idx & 31;
    int grow = r0 + row;
    ushort4 v0 = {0, 0, 0, 0}, v1 = {0, 0, 0, 0};
    if (grow < NN) {
      const ushort4* g = (const ushort4*)(A + (size_t)grow * DIM + seg * 8);
      v0 = g[0]; v1 = g[1];
    }
    *(ushort4*)(&As[row * LDSROW + seg * 8 + 0]) = v0;
    *(ushort4*)(&As[row * LDSROW + seg * 8 + 4]) = v1;
  }
  __syncthreads();

  int wave = tid >> 6, lane = tid & 63;
  int quad = lane >> 4, l16 = lane & 15;

  f32x4 acc[2][4];
#pragma unroll
  for (int mt = 0; mt < 2; ++mt)
#pragma unroll
    for (int nti = 0; nti < 4; ++nti)
      acc[mt][nti] = (f32x4){0.f, 0.f, 0.f, 0.f};

#pragma unroll
  for (int kc = 0; kc < 8; ++kc) {
    bf16x8 a[2], b[4];
#pragma unroll
    for (int mt = 0; mt < 2; ++mt)
      a[mt] = *(const bf16x8*)(&As[(mt * 16 + l16) * LDSROW + kc * 32 + quad * 8]);
#pragma unroll
    for (int nti = 0; nti < 4; ++nti) {
      int nt = wave * 4 + nti;
      b[nti] = *(const bf16x8*)(Wb + ((size_t)(nt * 8 + kc) * 64 + lane) * 8);
    }
#pragma unroll
    for (int mt = 0; mt < 2; ++mt)
#pragma unroll
      for (int nti = 0; nti < 4; ++nti)
        acc[mt][nti] = __builtin_amdgcn_mfma_f32_16x16x32_bf16(a[mt], b[nti], acc[mt][nti], 0, 0, 0);
  }

  float pa = *prelu_a_ptr;
  float bv[4], cs[4];
#pragma unroll
  for (int nti = 0; nti < 4; ++nti) {
    bv[nti] = bias[wave * 64 + nti * 16 + l16];
    cs[nti] = 0.f;
  }
#pragma unroll
  for (int mt = 0; mt < 2; ++mt) {
#pragma unroll
    for (int nti = 0; nti < 4; ++nti) {
#pragma unroll
      for (int r = 0; r < 4; ++r) {
        int rowg = r0 + mt * 16 + quad * 4 + r;
        float x = acc[mt][nti][r] + bv[nti];
        x = (x >= 0.f) ? x : pa * x;
        acc[mt][nti][r] = x;
        if (rowg < NN) cs[nti] += x;
      }
    }
  }
#pragma unroll
  for (int nti = 0; nti < 4; ++nti) {
    cs[nti] += __shfl_xor(cs[nti], 16, 64);
    cs[nti] += __shfl_xor(cs[nti], 32, 64);
  }
  if (quad == 0) {
#pragma unroll
    for (int nti = 0; nti < 4; ++nti)
      atomicAdd(&hg[wave * 64 + nti * 16 + l16], cs[nti]);
  }

  float* LF = (float*)As;  // [16][FROW]
#pragma unroll
  for (int chunk = 0; chunk < 2; ++chunk) {
    __syncthreads();
#pragma unroll
    for (int nti = 0; nti < 4; ++nti) {
      int colw = wave * 64 + nti * 16 + l16;
#pragma unroll
      for (int r = 0; r < 4; ++r)
        LF[(quad * 4 + r) * FROW + colw] = acc[chunk][nti][r];
    }
    __syncthreads();
    int rowbase = r0 + chunk * 16;
    if (C) {
#pragma unroll
      for (int s = 0; s < 4; ++s) {
        int g = s * 256 + tid;
        int row = g >> 6, cg = g & 63;
        int rowg = rowbase + row;
        if (rowg < NN) {
          float4 v = *(const float4*)&LF[row * FROW + cg * 4];
          *(float4*)(C + (size_t)rowg * DIM + cg * 4) = v;
        }
      }
    }
    if (Cb) {
#pragma unroll
      for (int s = 0; s < 2; ++s) {
        int g = s * 256 + tid;
        int row = g >> 5, cg = g & 31;
        int rowg = rowbase + row;
        if (rowg < NN) {
          float ns = norm_s[rowg];
          float4 v0 = *(const float4*)&LF[row * FROW + cg * 8];
          float4 v1 = *(const float4*)&LF[row * FROW + cg * 8 + 4];
          uint4 o;
          o.x = (unsigned)f2bf(v0.x * ns) | ((unsigned)f2bf(v0.y * ns) << 16);
          o.y = (unsigned)f2bf(v0.z * ns) | ((unsigned)f2bf(v0.w * ns) << 16);
          o.z = (unsigned)f2bf(v1.x * ns) | ((unsigned)f2bf(v1.y * ns) << 16);
          o.w = (unsigned)f2bf(v1.z * ns) | ((unsigned)f2bf(v1.w * ns) << 16);
          *(uint4*)(Cb + (size_t)rowg * DIM + cg * 8) = o;
        }
      }
    }
  }
}

extern "C" void kernel_launch(void* const* d_in, const int* in_sizes, int n_in,
                              void* d_out, int out_size, void* d_ws, size_t ws_size,
                              hipStream_t stream) {
  const float* feat = (const float*)d_in[0];
  const int* src    = (const int*)d_in[1];
  const int* dst    = (const int*)d_in[2];
  const float* W0   = (const float*)d_in[3];
  const float* b0   = (const float*)d_in[4];
  const float* W1   = (const float*)d_in[5];
  const float* b1   = (const float*)d_in[6];
  const float* pa   = (const float*)d_in[7];

  float* out_h = (float*)d_out;                      // [NN, DIM] f32
  float* hg    = out_h + (size_t)NN * DIM;           // [512] f32

  char* w = (char*)d_ws;
  int* in_cnt   = (int*)w;        w += (size_t)NN * 4;
  float* norm_s = (float*)w;      w += (size_t)NN * 4;
  float* norm_d = (float*)w;      w += (size_t)NN * 4;
  int* row_ptr  = (int*)w;        w += (size_t)(NN + 1) * 4;
  int* colx     = (int*)w;        w += (size_t)NE * 4;
  unsigned short* Wb0 = (unsigned short*)w;  w += (size_t)DIM * DIM * 2;
  unsigned short* Wb1 = (unsigned short*)w;  w += (size_t)DIM * DIM * 2;
  uintptr_t ap = ((uintptr_t)w + 255) & ~(uintptr_t)255;
  unsigned short* featb = (unsigned short*)ap;                 // [NN,DIM] bf16 (pre-scaled; reused as h1b)
  unsigned short* aggb  = featb + (size_t)NN * DIM;            // [NN,DIM] bf16
  // aliases (dead before their region's first real use):
  unsigned* Hs = (unsigned*)featb;               // [HB][25000 words] = 12.8 MB
  unsigned* Hd = Hs + (size_t)HB * HALF;         // [HB][25000 words] = 12.8 MB
  unsigned* Pd = (unsigned*)aggb;                // [HB][25000 words] = 12.8 MB (dead after fill)

  hist_kernel<<<HB, HT, 0, stream>>>(src, dst, Hs, Hd);
  reduce_norm_kernel<<<(2 * HWORDS + 255) / 256, 256, 0, stream>>>(Hs, Hd, Pd, in_cnt,
                                                                   norm_s, norm_d, hg);
  prep_kernel<<<12564, 256, 0, stream>>>(feat, norm_s, featb, W0, Wb0, W1, Wb1);
  scan_kernel<<<1, 1024, 0, stream>>>(in_cnt, row_ptr);
  fill_kernel<<<HB, HT, 0, stream>>>(src, dst, row_ptr, Pd, colx);

  // layer 1: only the scaled-bf16 h1 is live
  agg_kernel<<<(NN + 3) / 4, 256, 0, stream>>>(featb, aggb, row_ptr, colx, norm_d);
  gemm_mfma_kernel<<<(NN + 31) / 32, 256, 0, stream>>>(aggb, Wb0, b0, pa, norm_s,
                                                       (float*)nullptr, featb, hg);

  // layer 2: f32 output only
  agg_kernel<<<(NN + 3) / 4, 256, 0, stream>>>(featb, aggb, row_ptr, colx, norm_d);
  gemm_mfma_kernel<<<(NN + 31) / 32, 256, 0, stream>>>(aggb, Wb1, b1, pa, norm_s,
                                                       out_h, (unsigned short*)nullptr, hg + 256);
}